// Round 1
// baseline (380.127 us; speedup 1.0000x reference)
//
#include <hip/hip_runtime.h>
#include <hip/hip_bf16.h>

#define PI2 6.283185307179586f

// ---------------- workspace layout (float offsets) ----------------
static const size_t O_Y      = 0;          // 9*4096 harmonics
static const size_t O_W1RT   = 36864;      // 512  w1 real, transposed [c][j]
static const size_t O_W1IT   = 37376;      // 512
static const size_t O_W1XR   = 37888;      // 512  (w1 @ w_fno) real [c][j]
static const size_t O_W1XI   = 38400;      // 512
static const size_t O_B1PR   = 38912;      // 16   w1@b_fno + b1
static const size_t O_B1PI   = 38928;      // 16
static const size_t O_WSH    = 38944;      // 16   1/sqrt(cnt)
static const size_t O_SHELL  = 38960;      // int[4096]
static const size_t O_ORDER  = 43056;      // int[4096]
static const size_t O_SSTART = 47152;      // int[32]
static const size_t O_COEF   = 47232;      // 2*32*144*2
static const size_t O_COEF2  = 65664;      // 2*32*144*2
static const size_t O_XS     = 84096;      // 2*32*4096*2
static const size_t O_XS2    = 608384;     // 2*32*4096*2
static const size_t O_T2     = 1132672;    // 2*32*64*16*16*2  (reused as U1)
static const size_t O_T1     = 3229824;    // 2*32*64*64*16*2  (reused as U2)
// total 11618432 floats = 46.5 MB

static __device__ __forceinline__ float geluf(float v) {
  // tanh-approx gelu (jax.nn.gelu approximate=True)
  float u = 0.7978845608028654f * (v + 0.044715f * v * v * v);
  float a = fabsf(u);
  float e = __expf(-2.0f * a);
  float th = (1.0f - e) / (1.0f + e);
  th = copysignf(th, u);
  return 0.5f * v * (1.0f + th);
}

// ---------------- K0: tables + folded weights (1 block) ----------------
__global__ __launch_bounds__(256) void k0_init(
    const float* __restrict__ wfr, const float* __restrict__ wfi,
    const float* __restrict__ bfr, const float* __restrict__ bfi,
    const float* __restrict__ w1r, const float* __restrict__ w1i,
    const float* __restrict__ b1r, const float* __restrict__ b1i,
    float* __restrict__ ws) {
  float* Y    = ws + O_Y;
  float* w1rt = ws + O_W1RT;  float* w1it = ws + O_W1IT;
  float* W1xr = ws + O_W1XR;  float* W1xi = ws + O_W1XI;
  float* b1pr = ws + O_B1PR;  float* b1pi = ws + O_B1PI;
  float* wsh  = ws + O_WSH;
  int* shellOf = (int*)(ws + O_SHELL);
  int* order   = (int*)(ws + O_ORDER);
  int* sstart  = (int*)(ws + O_SSTART);

  __shared__ int cnt[16], fill[16], st[17];
  int tid = threadIdx.x;
  if (tid < 16) { cnt[tid] = 0; fill[tid] = 0; }
  __syncthreads();
  for (int m = tid; m < 4096; m += 256) {
    int ix = m >> 8, iy = (m >> 4) & 15, iz = m & 15;
    float kx = (float)(ix < 8 ? ix : ix - 16);
    float ky = (float)(iy < 8 ? iy : iy - 16);
    float kz = (float)(iz < 8 ? iz : iz - 16);
    float r2 = kx*kx + ky*ky + kz*kz;
    float r  = sqrtf(r2);
    float nzm = r2 > 0.f ? 1.f : 0.f;
    float inv = r2 > 0.f ? 1.0f / fmaxf(r, 1e-9f) : 0.f;
    float ux = kx*inv, uy = ky*inv, uz = kz*inv;
    Y[0*4096+m] = 0.282095f;
    Y[1*4096+m] = 0.488603f * uy;
    Y[2*4096+m] = 0.488603f * uz;
    Y[3*4096+m] = 0.488603f * ux;
    Y[4*4096+m] = 1.092548f * ux*uy;
    Y[5*4096+m] = 1.092548f * uy*uz;
    Y[6*4096+m] = 0.315392f * (3.0f*uz*uz - nzm);
    Y[7*4096+m] = 1.092548f * ux*uz;
    Y[8*4096+m] = 0.546274f * (ux*ux - uy*uy);
    // replicate numpy fp32 op order exactly for the discrete shell binning
    float rmax = sqrtf(192.0f);           // == r.max() (exact sqrt of exact max r2)
    float t = r / (rmax + 1e-6f) * 16.0f;
    int sh = (int)t; sh = sh > 15 ? 15 : sh;
    shellOf[m] = sh;
    atomicAdd(&cnt[sh], 1);
  }
  __syncthreads();
  if (tid == 0) { int a = 0; for (int s = 0; s < 16; ++s) { st[s] = a; a += cnt[s]; } st[16] = a; }
  __syncthreads();
  if (tid < 16) wsh[tid] = 1.0f / sqrtf(fmaxf((float)cnt[tid], 1.0f));
  if (tid < 17) sstart[tid] = st[tid];
  for (int m = tid; m < 4096; m += 256) {
    int sh = shellOf[m];
    int p = atomicAdd(&fill[sh], 1);
    order[st[sh] + p] = m;
  }
  // fold skip_fno into the MLP: W1x = w1 @ w_fno, b1p = w1 @ b_fno + b1
  for (int e = tid; e < 512; e += 256) {
    int j = e >> 5, c = e & 31;
    float ar = 0.f, ai = 0.f;
    for (int o = 0; o < 32; ++o) {
      float wr_ = w1r[j*32+o], wi_ = w1i[j*32+o];
      float fr  = wfr[o*32+c], fi_ = wfi[o*32+c];
      ar += wr_*fr - wi_*fi_;
      ai += wr_*fi_ + wi_*fr;
    }
    W1xr[c*16+j] = ar;  W1xi[c*16+j] = ai;
    w1rt[c*16+j] = w1r[j*32+c];
    w1it[c*16+j] = w1i[j*32+c];
  }
  if (tid < 16) {
    int j = tid;
    float ar = b1r[j], ai = b1i[j];
    for (int o = 0; o < 32; ++o) {
      ar += w1r[j*32+o]*bfr[o] - w1i[j*32+o]*bfi[o];
      ai += w1r[j*32+o]*bfi[o] + w1i[j*32+o]*bfr[o];
    }
    b1pr[j] = ar; b1pi[j] = ai;
  }
}

// ---------------- K1: forward partial DFT along z (real input) ----------------
// grid 4096 = (b*32+c)*64 + x ; x[bc][x][y][z] -> T1[bc][x][y][kz] (cplx)
__global__ __launch_bounds__(256) void k1_dftz(const float* __restrict__ x, float* __restrict__ T1) {
  __shared__ float plane[64*68];            // [z][y], pad 68 keeps b128 aligned
  int blk = blockIdx.x;
  const float* src = x + (size_t)blk * 4096;
  int tid = threadIdx.x;
  for (int i = tid; i < 4096; i += 256) {
    int y = i >> 6, z = i & 63;
    plane[z*68 + y] = src[i];
  }
  __syncthreads();
  int kz = tid & 15, yq = tid >> 4;         // thread: 1 kz, 4 consecutive y
  float f = (float)(kz < 8 ? kz : kz - 16);
  float ang = -PI2 * f / 64.0f;
  float sw, cw; __sincosf(ang, &sw, &cw);
  float tr = 1.f, ti = 0.f;
  float a0r=0,a0i=0,a1r=0,a1i=0,a2r=0,a2i=0,a3r=0,a3i=0;
  for (int z = 0; z < 64; ++z) {
    float4 xv = *(const float4*)&plane[z*68 + 4*yq];
    a0r += xv.x*tr; a0i += xv.x*ti;
    a1r += xv.y*tr; a1i += xv.y*ti;
    a2r += xv.z*tr; a2i += xv.z*ti;
    a3r += xv.w*tr; a3i += xv.w*ti;
    float nt = tr*cw - ti*sw; ti = tr*sw + ti*cw; tr = nt;
  }
  float* dst = T1 + (size_t)blk * 2048;
  int y0 = 4*yq;
  *(float2*)&dst[((y0+0)*16 + kz)*2] = make_float2(a0r, a0i);
  *(float2*)&dst[((y0+1)*16 + kz)*2] = make_float2(a1r, a1i);
  *(float2*)&dst[((y0+2)*16 + kz)*2] = make_float2(a2r, a2i);
  *(float2*)&dst[((y0+3)*16 + kz)*2] = make_float2(a3r, a3i);
}

// ---------------- K2: forward partial DFT along y ----------------
// grid 4096 = bc*64 + x ; T1[bc][x][y][kz] -> T2[bc][x][ky][kz]
__global__ __launch_bounds__(256) void k2_dfty(const float* __restrict__ T1, float* __restrict__ T2) {
  __shared__ float slab[2048];
  int blk = blockIdx.x;
  int tid = threadIdx.x;
  const float* src = T1 + (size_t)blk * 2048;
  for (int i = tid; i < 2048; i += 256) slab[i] = src[i];
  __syncthreads();
  int kz = tid & 15, kyi = tid >> 4;
  float f = (float)(kyi < 8 ? kyi : kyi - 16);
  float ang = -PI2 * f / 64.0f;
  float sw, cw; __sincosf(ang, &sw, &cw);
  float tr=1.f, ti=0.f, ar=0.f, ai=0.f;
  for (int y = 0; y < 64; ++y) {
    float2 v = *(const float2*)&slab[(y*16 + kz)*2];
    ar += v.x*tr - v.y*ti;
    ai += v.x*ti + v.y*tr;
    float nt = tr*cw - ti*sw; ti = tr*sw + ti*cw; tr = nt;
  }
  *(float2*)&T2[(size_t)blk*512 + (kyi*16 + kz)*2] = make_float2(ar, ai);
}

// ---------------- K3: forward partial DFT along x ----------------
// grid 1024 = bc*16 + ky ; T2[bc][x][ky][kz] -> xs[bc][m], m=(kx*16+ky)*16+kz
__global__ __launch_bounds__(256) void k3_dftx(const float* __restrict__ T2, float* __restrict__ xs) {
  __shared__ float slab[2048];               // [x][kz] cplx for fixed ky
  int blk = blockIdx.x;
  int bc = blk >> 4, ky = blk & 15;
  int tid = threadIdx.x;
  for (int i = tid; i < 2048; i += 256) {
    int xr = i >> 5, rem = i & 31;
    slab[i] = T2[((size_t)(bc*64 + xr)*16 + ky)*32 + rem];
  }
  __syncthreads();
  int kz = tid & 15, kxi = tid >> 4;
  float f = (float)(kxi < 8 ? kxi : kxi - 16);
  float ang = -PI2 * f / 64.0f;
  float sw, cw; __sincosf(ang, &sw, &cw);
  float tr=1.f, ti=0.f, ar=0.f, ai=0.f;
  for (int xr = 0; xr < 64; ++xr) {
    float2 v = *(const float2*)&slab[(xr*16 + kz)*2];
    ar += v.x*tr - v.y*ti;
    ai += v.x*ti + v.y*tr;
    float nt = tr*cw - ti*sw; ti = tr*sw + ti*cw; tr = nt;
  }
  *(float2*)&xs[(size_t)bc*8192 + (kxi*256 + ky*16 + kz)*2] = make_float2(ar, ai);
}

// ---------------- K4: project onto (shell, harmonic) basis ----------------
// grid 1024 = bc*16 + shell ; coeffs[bc][s][l] = w[s] * sum_{m in shell} xs[m]*Y[l][m]
__global__ __launch_bounds__(256) void k4_proj(const float* __restrict__ xs, const float* __restrict__ Y,
    const int* __restrict__ order, const int* __restrict__ sstart, const float* __restrict__ wsh,
    float* __restrict__ coeffs) {
  int blk = blockIdx.x; int bc = blk >> 4, s = blk & 15;
  int tid = threadIdx.x;
  int st = sstart[s], en = sstart[s+1];
  float ar[9], ai[9];
  #pragma unroll
  for (int l = 0; l < 9; ++l) { ar[l] = 0.f; ai[l] = 0.f; }
  for (int ii = st + tid; ii < en; ii += 256) {
    int m = order[ii];
    float2 v = *(const float2*)&xs[(size_t)bc*8192 + m*2];
    #pragma unroll
    for (int l = 0; l < 9; ++l) {
      float yv = Y[l*4096 + m];
      ar[l] += yv * v.x; ai[l] += yv * v.y;
    }
  }
  __shared__ float red[256*19];
  #pragma unroll
  for (int l = 0; l < 9; ++l) { red[tid*19 + l] = ar[l]; red[tid*19 + 9 + l] = ai[l]; }
  __syncthreads();
  for (int r = 128; r >= 1; r >>= 1) {
    if (tid < r) {
      #pragma unroll
      for (int q = 0; q < 18; ++q) red[tid*19 + q] += red[(tid + r)*19 + q];
    }
    __syncthreads();
  }
  if (tid == 0) {
    float w = wsh[s];
    for (int l = 0; l < 9; ++l) {
      coeffs[((size_t)bc*144 + s*9 + l)*2]     = w * red[l];
      coeffs[((size_t)bc*144 + s*9 + l)*2 + 1] = w * red[9 + l];
    }
  }
}

// ---------------- K5: complex spectral conv + ifft normalization ----------------
// grid 288 = b*144 + (s*9+l) ; coeffs2[b][o][sl] = (1/64^3) * sum_i coeffs[b][i][sl]*wspec[sl][i][o]
__global__ __launch_bounds__(64) void k5_spec(const float* __restrict__ coeffs,
    const float* __restrict__ wsr, const float* __restrict__ wsi, float* __restrict__ coeffs2) {
  int blk = blockIdx.x;
  int b = blk / 144, sl = blk % 144;
  int o = threadIdx.x;
  if (o >= 32) return;
  float ar = 0.f, ai = 0.f;
  for (int i = 0; i < 32; ++i) {
    float cr = coeffs[((size_t)(b*32 + i)*144 + sl)*2];
    float ci = coeffs[((size_t)(b*32 + i)*144 + sl)*2 + 1];
    float wr = wsr[(sl*32 + i)*32 + o];
    float wi = wsi[(sl*32 + i)*32 + o];
    ar += cr*wr - ci*wi;
    ai += cr*wi + ci*wr;
  }
  const float sc = 1.0f / 262144.0f;
  coeffs2[((size_t)(b*32 + o)*144 + sl)*2]     = ar * sc;
  coeffs2[((size_t)(b*32 + o)*144 + sl)*2 + 1] = ai * sc;
}

// ---------------- K7: back-project to modes ----------------
// grid 1024 = bo*16 + chunk ; xs2[bo][m] = w[sh(m)] * sum_l coeffs2[bo][sh*9+l]*Y[l][m]
__global__ __launch_bounds__(256) void k7_unproj(const float* __restrict__ coeffs2, const float* __restrict__ Y,
    const int* __restrict__ shellOf, const float* __restrict__ wsh, float* __restrict__ xs2) {
  int bo = blockIdx.x >> 4;
  int m = ((blockIdx.x & 15) << 8) | threadIdx.x;
  __shared__ float c2[288];
  for (int i = threadIdx.x; i < 288; i += 256) c2[i] = coeffs2[(size_t)bo*288 + i];
  __syncthreads();
  int sh = shellOf[m];
  float w = wsh[sh];
  float ar = 0.f, ai = 0.f;
  #pragma unroll
  for (int l = 0; l < 9; ++l) {
    float yv = Y[l*4096 + m];
    ar += yv * c2[(sh*9 + l)*2];
    ai += yv * c2[(sh*9 + l)*2 + 1];
  }
  xs2[(size_t)bo*8192 + m*2]     = w * ar;
  xs2[(size_t)bo*8192 + m*2 + 1] = w * ai;
}

// ---------------- K8: inverse partial DFT along x ----------------
// grid 1024 = bo*16 + ky ; xs2[bo][m] -> U1[bo][x][ky][kz]
__global__ __launch_bounds__(256) void k8_invx(const float* __restrict__ xs2, float* __restrict__ U1) {
  __shared__ float slab[512];                 // [kx][kz] cplx for fixed ky
  int blk = blockIdx.x;
  int bo = blk >> 4, ky = blk & 15;
  int tid = threadIdx.x;
  for (int i = tid; i < 512; i += 256) {
    int kx = i >> 5, rem = i & 31;
    slab[i] = xs2[(size_t)bo*8192 + kx*512 + ky*32 + rem];
  }
  __syncthreads();
  int kz = tid & 15, grp = tid >> 4;          // outputs x = grp + 16q
  float tr4[4], ti4[4], wr4[4], wi4[4], ar4[4], ai4[4];
  #pragma unroll
  for (int q = 0; q < 4; ++q) {
    int xx = grp + 16*q;
    float ang = PI2 * (float)xx / 64.0f;
    __sincosf(ang, &wi4[q], &wr4[q]);
    tr4[q] = 1.f; ti4[q] = 0.f; ar4[q] = 0.f; ai4[q] = 0.f;
  }
  #pragma unroll
  for (int kx = 0; kx < 16; ++kx) {
    if (kx == 8) { ti4[0] = -ti4[0]; ti4[1] = -ti4[1]; ti4[2] = -ti4[2]; ti4[3] = -ti4[3]; }
    float2 v = *(const float2*)&slab[(kx*16 + kz)*2];
    #pragma unroll
    for (int q = 0; q < 4; ++q) {
      ar4[q] += v.x*tr4[q] - v.y*ti4[q];
      ai4[q] += v.x*ti4[q] + v.y*tr4[q];
      float nt = tr4[q]*wr4[q] - ti4[q]*wi4[q];
      ti4[q] = tr4[q]*wi4[q] + ti4[q]*wr4[q];
      tr4[q] = nt;
    }
  }
  #pragma unroll
  for (int q = 0; q < 4; ++q) {
    int xx = grp + 16*q;
    *(float2*)&U1[((size_t)(bo*64 + xx)*16 + ky)*32 + kz*2] = make_float2(ar4[q], ai4[q]);
  }
}

// ---------------- K9: inverse partial DFT along y ----------------
// grid 4096 = bo*64 + x ; U1[bo][x][ky][kz] -> U2[bo][x][y][kz]
__global__ __launch_bounds__(256) void k9_invy(const float* __restrict__ U1, float* __restrict__ U2) {
  __shared__ float slab[512];
  int blk = blockIdx.x;
  int tid = threadIdx.x;
  const float* src = U1 + (size_t)blk * 512;
  for (int i = tid; i < 512; i += 256) slab[i] = src[i];
  __syncthreads();
  int kz = tid & 15, grp = tid >> 4;
  float tr4[4], ti4[4], wr4[4], wi4[4], ar4[4], ai4[4];
  #pragma unroll
  for (int q = 0; q < 4; ++q) {
    int yy = grp + 16*q;
    float ang = PI2 * (float)yy / 64.0f;
    __sincosf(ang, &wi4[q], &wr4[q]);
    tr4[q] = 1.f; ti4[q] = 0.f; ar4[q] = 0.f; ai4[q] = 0.f;
  }
  #pragma unroll
  for (int ky = 0; ky < 16; ++ky) {
    if (ky == 8) { ti4[0] = -ti4[0]; ti4[1] = -ti4[1]; ti4[2] = -ti4[2]; ti4[3] = -ti4[3]; }
    float2 v = *(const float2*)&slab[(ky*16 + kz)*2];
    #pragma unroll
    for (int q = 0; q < 4; ++q) {
      ar4[q] += v.x*tr4[q] - v.y*ti4[q];
      ai4[q] += v.x*ti4[q] + v.y*tr4[q];
      float nt = tr4[q]*wr4[q] - ti4[q]*wi4[q];
      ti4[q] = tr4[q]*wi4[q] + ti4[q]*wr4[q];
      tr4[q] = nt;
    }
  }
  float* dst = U2 + (size_t)blk * 2048;
  #pragma unroll
  for (int q = 0; q < 4; ++q) {
    int yy = grp + 16*q;
    *(float2*)&dst[(yy*16 + kz)*2] = make_float2(ar4[q], ai4[q]);
  }
}

// ---------------- K10: inverse-z DFT + MLP + skips, fused epilogue ----------------
// grid 2048 = (b*64 + x)*16 + yblock(4 y-lines) ; 256 threads
__global__ __launch_bounds__(256) void k10_final(
    const float* __restrict__ x, const float* __restrict__ U2,
    const float* __restrict__ ws,
    const float* __restrict__ w2r, const float* __restrict__ w2i,
    const float* __restrict__ b2r, const float* __restrict__ wgr,
    float* __restrict__ out) {
  const float* w1rt = ws + O_W1RT;  const float* w1it = ws + O_W1IT;
  const float* W1xr = ws + O_W1XR;  const float* W1xi = ws + O_W1XI;
  const float* b1pr = ws + O_B1PR;  const float* b1pi = ws + O_B1PI;

  __shared__ __hip_bfloat16 xline[4*32*64];            // [y][c][z]
  __shared__ __hip_bfloat16 xfr[4*32*66], xfi[4*32*66]; // x_fno, stride-66 pad

  int tid = threadIdx.x;
  int blk = blockIdx.x;
  int yb = blk & 15, bx = blk >> 4;
  int b = bx >> 6, xr = bx & 63;
  int y0 = yb * 4;

  for (int i = tid; i < 8192; i += 256) {
    int y = i >> 11, c = (i >> 6) & 31, z = i & 63;
    float v = x[(size_t)(b*32 + c)*262144 + (size_t)xr*4096 + (size_t)(y0 + y)*64 + z];
    xline[(y*32 + c)*64 + z] = __float2bfloat16(v);
  }
  __syncthreads();

  // Stage A: x_fno[o][z] = sum_kz U2[o][kz] e^{+2pi i f(kz) z/64}; z/z+32 parity pairing
  {
    int o = tid & 31, g = tid >> 5;
    int ya = g >> 1, zh = g & 1;
    size_t base = ((size_t)((b*32 + o)*64 + xr)*64 + (size_t)(y0 + ya))*32;
    float ur[16], ui[16];
    const float4* u4 = (const float4*)(U2 + base);
    #pragma unroll
    for (int q = 0; q < 8; ++q) {
      float4 v = u4[q];
      ur[2*q] = v.x; ui[2*q] = v.y; ur[2*q+1] = v.z; ui[2*q+1] = v.w;
    }
    for (int zz = 0; zz < 16; ++zz) {
      int z = zh*16 + zz;
      float ang = PI2 * (float)z / 64.0f;
      float sw, cw; __sincosf(ang, &sw, &cw);
      float tr = 1.f, ti = 0.f;
      float er = 0.f, ei = 0.f, odr = 0.f, odi = 0.f;
      #pragma unroll
      for (int kz = 0; kz < 16; ++kz) {
        if (kz == 8) ti = -ti;                 // f jumps from +8 to -8: conjugate
        float pr  = ur[kz]*tr - ui[kz]*ti;
        float pi_ = ur[kz]*ti + ui[kz]*tr;
        if (kz & 1) { odr += pr; odi += pi_; } else { er += pr; ei += pi_; }
        float nt = tr*cw - ti*sw; ti = tr*sw + ti*cw; tr = nt;
      }
      int c0 = (ya*32 + o)*66;
      xfr[c0 + z]      = __float2bfloat16(er + odr);
      xfi[c0 + z]      = __float2bfloat16(ei + odi);
      xfr[c0 + z + 32] = __float2bfloat16(er - odr);
      xfi[c0 + z + 32] = __float2bfloat16(ei - odi);
    }
  }
  __syncthreads();

  // Stage B: per point: h = gelu(w1@x_fno + W1x@x + b1'); out = Re(w2@h)+b2r + x*w_gate_r
  {
    int z = tid & 63, ya = tid >> 6;
    float hr[16], hi[16];
    #pragma unroll
    for (int j = 0; j < 16; ++j) { hr[j] = b1pr[j]; hi[j] = b1pi[j]; }
    for (int c = 0; c < 32; ++c) {
      int c0 = ya*32 + c;
      float fr = __bfloat162float(xfr[c0*66 + z]);
      float fi = __bfloat162float(xfi[c0*66 + z]);
      float xv = __bfloat162float(xline[c0*64 + z]);
      const float* w1r_c = w1rt + c*16;
      const float* w1i_c = w1it + c*16;
      const float* Wr_c  = W1xr + c*16;
      const float* Wi_c  = W1xi + c*16;
      #pragma unroll
      for (int j = 0; j < 16; ++j) {
        hr[j] += w1r_c[j]*fr - w1i_c[j]*fi + Wr_c[j]*xv;
        hi[j] += w1r_c[j]*fi + w1i_c[j]*fr + Wi_c[j]*xv;
      }
    }
    #pragma unroll
    for (int j = 0; j < 16; ++j) { hr[j] = geluf(hr[j]); hi[j] = geluf(hi[j]); }
    for (int o = 0; o < 32; ++o) {
      const float* w2r_o = w2r + o*16;
      const float* w2i_o = w2i + o*16;
      float acc = b2r[o];
      #pragma unroll
      for (int j = 0; j < 16; ++j) acc += w2r_o[j]*hr[j] - w2i_o[j]*hi[j];
      float xv = __bfloat162float(xline[(ya*32 + o)*64 + z]);
      out[(size_t)(b*32 + o)*262144 + (size_t)xr*4096 + (size_t)(y0 + ya)*64 + z] = acc + xv*wgr[o];
    }
  }
}

// ---------------- launch ----------------
extern "C" void kernel_launch(void* const* d_in, const int* in_sizes, int n_in,
                              void* d_out, int out_size, void* d_ws, size_t ws_size,
                              hipStream_t stream) {
  (void)in_sizes; (void)n_in; (void)out_size; (void)ws_size;
  const float* x   = (const float*)d_in[0];
  const float* wfr = (const float*)d_in[1];
  const float* wfi = (const float*)d_in[2];
  const float* bfr = (const float*)d_in[3];
  const float* bfi = (const float*)d_in[4];
  const float* wgr = (const float*)d_in[5];
  const float* wsr = (const float*)d_in[7];
  const float* wsi = (const float*)d_in[8];
  const float* w1r = (const float*)d_in[9];
  const float* w1i = (const float*)d_in[10];
  const float* b1r = (const float*)d_in[11];
  const float* b1i = (const float*)d_in[12];
  const float* w2r = (const float*)d_in[13];
  const float* w2i = (const float*)d_in[14];
  const float* b2r = (const float*)d_in[15];
  float* out = (float*)d_out;
  float* ws  = (float*)d_ws;

  float* T1      = ws + O_T1;    // also U2
  float* T2      = ws + O_T2;    // also U1
  float* xs      = ws + O_XS;
  float* xs2     = ws + O_XS2;
  float* coeffs  = ws + O_COEF;
  float* coeffs2 = ws + O_COEF2;
  float* Y       = ws + O_Y;
  int* shellOf   = (int*)(ws + O_SHELL);
  int* order     = (int*)(ws + O_ORDER);
  int* sstart    = (int*)(ws + O_SSTART);
  float* wsh     = ws + O_WSH;

  hipLaunchKernelGGL(k0_init,  dim3(1),    dim3(256), 0, stream, wfr, wfi, bfr, bfi, w1r, w1i, b1r, b1i, ws);
  hipLaunchKernelGGL(k1_dftz,  dim3(4096), dim3(256), 0, stream, x, T1);
  hipLaunchKernelGGL(k2_dfty,  dim3(4096), dim3(256), 0, stream, T1, T2);
  hipLaunchKernelGGL(k3_dftx,  dim3(1024), dim3(256), 0, stream, T2, xs);
  hipLaunchKernelGGL(k4_proj,  dim3(1024), dim3(256), 0, stream, xs, Y, order, sstart, wsh, coeffs);
  hipLaunchKernelGGL(k5_spec,  dim3(288),  dim3(64),  0, stream, coeffs, wsr, wsi, coeffs2);
  hipLaunchKernelGGL(k7_unproj,dim3(1024), dim3(256), 0, stream, coeffs2, Y, shellOf, wsh, xs2);
  hipLaunchKernelGGL(k8_invx,  dim3(1024), dim3(256), 0, stream, xs2, T2);
  hipLaunchKernelGGL(k9_invy,  dim3(4096), dim3(256), 0, stream, T2, T1);
  hipLaunchKernelGGL(k10_final,dim3(2048), dim3(256), 0, stream, x, T1, ws, w2r, w2i, b2r, wgr, out);
}

// Round 2
// 351.339 us; speedup vs baseline: 1.0819x; 1.0819x over previous
//
#include <hip/hip_runtime.h>
#include <hip/hip_bf16.h>

#define PI2 6.283185307179586f

// ---------------- workspace layout (float offsets) ----------------
static const size_t O_Y      = 0;          // 9*4096 harmonics
static const size_t O_W1RT   = 36864;      // 512  w1 real, transposed [c][j]
static const size_t O_W1IT   = 37376;      // 512
static const size_t O_W1XR   = 37888;      // 512  (w1 @ w_fno) real [c][j]
static const size_t O_W1XI   = 38400;      // 512
static const size_t O_B1PR   = 38912;      // 16   w1@b_fno + b1
static const size_t O_B1PI   = 38928;      // 16
static const size_t O_WSH    = 38944;      // 16   1/sqrt(cnt)
static const size_t O_SHELL  = 38960;      // int[4096]
static const size_t O_ORDER  = 43056;      // int[4096]
static const size_t O_SSTART = 47152;      // int[32]
static const size_t O_COEF   = 47232;      // 2*32*144*2
static const size_t O_COEF2  = 65664;      // 2*32*144*2
static const size_t O_XS     = 84096;      // 2*32*4096*2
static const size_t O_XS2    = 608384;     // 2*32*4096*2
static const size_t O_T2     = 1132672;    // 2*32*64*16*16*2  (reused as U1)
static const size_t O_T1     = 3229824;    // 2*32*64*64*16*2  (reused as U2)
// total 11618432 floats = 46.5 MB

static __device__ __forceinline__ float geluf(float v) {
  // tanh-approx gelu (jax.nn.gelu approximate=True)
  float u = 0.7978845608028654f * (v + 0.044715f * v * v * v);
  float a = fabsf(u);
  float e = __expf(-2.0f * a);
  float th = (1.0f - e) / (1.0f + e);
  th = copysignf(th, u);
  return 0.5f * v * (1.0f + th);
}

static __device__ __forceinline__ unsigned int f2bfbits(float f) {
  // RNE f32 -> bf16 bits (matches __float2bfloat16 for normal values)
  unsigned int u = __float_as_uint(f);
  u += 0x7fffu + ((u >> 16) & 1u);
  return u >> 16;
}

// ---------------- K0: tables + folded weights (1 block) ----------------
__global__ __launch_bounds__(256) void k0_init(
    const float* __restrict__ wfr, const float* __restrict__ wfi,
    const float* __restrict__ bfr, const float* __restrict__ bfi,
    const float* __restrict__ w1r, const float* __restrict__ w1i,
    const float* __restrict__ b1r, const float* __restrict__ b1i,
    float* __restrict__ ws) {
  float* Y    = ws + O_Y;
  float* w1rt = ws + O_W1RT;  float* w1it = ws + O_W1IT;
  float* W1xr = ws + O_W1XR;  float* W1xi = ws + O_W1XI;
  float* b1pr = ws + O_B1PR;  float* b1pi = ws + O_B1PI;
  float* wsh  = ws + O_WSH;
  int* shellOf = (int*)(ws + O_SHELL);
  int* order   = (int*)(ws + O_ORDER);
  int* sstart  = (int*)(ws + O_SSTART);

  __shared__ int cnt[16], fill[16], st[17];
  int tid = threadIdx.x;
  if (tid < 16) { cnt[tid] = 0; fill[tid] = 0; }
  __syncthreads();
  for (int m = tid; m < 4096; m += 256) {
    int ix = m >> 8, iy = (m >> 4) & 15, iz = m & 15;
    float kx = (float)(ix < 8 ? ix : ix - 16);
    float ky = (float)(iy < 8 ? iy : iy - 16);
    float kz = (float)(iz < 8 ? iz : iz - 16);
    float r2 = kx*kx + ky*ky + kz*kz;
    float r  = sqrtf(r2);
    float nzm = r2 > 0.f ? 1.f : 0.f;
    float inv = r2 > 0.f ? 1.0f / fmaxf(r, 1e-9f) : 0.f;
    float ux = kx*inv, uy = ky*inv, uz = kz*inv;
    Y[0*4096+m] = 0.282095f;
    Y[1*4096+m] = 0.488603f * uy;
    Y[2*4096+m] = 0.488603f * uz;
    Y[3*4096+m] = 0.488603f * ux;
    Y[4*4096+m] = 1.092548f * ux*uy;
    Y[5*4096+m] = 1.092548f * uy*uz;
    Y[6*4096+m] = 0.315392f * (3.0f*uz*uz - nzm);
    Y[7*4096+m] = 1.092548f * ux*uz;
    Y[8*4096+m] = 0.546274f * (ux*ux - uy*uy);
    // replicate numpy fp32 op order exactly for the discrete shell binning
    float rmax = sqrtf(192.0f);           // == r.max() (exact sqrt of exact max r2)
    float t = r / (rmax + 1e-6f) * 16.0f;
    int sh = (int)t; sh = sh > 15 ? 15 : sh;
    shellOf[m] = sh;
    atomicAdd(&cnt[sh], 1);
  }
  __syncthreads();
  if (tid == 0) { int a = 0; for (int s = 0; s < 16; ++s) { st[s] = a; a += cnt[s]; } st[16] = a; }
  __syncthreads();
  if (tid < 16) wsh[tid] = 1.0f / sqrtf(fmaxf((float)cnt[tid], 1.0f));
  if (tid < 17) sstart[tid] = st[tid];
  for (int m = tid; m < 4096; m += 256) {
    int sh = shellOf[m];
    int p = atomicAdd(&fill[sh], 1);
    order[st[sh] + p] = m;
  }
  // fold skip_fno into the MLP: W1x = w1 @ w_fno, b1p = w1 @ b_fno + b1
  for (int e = tid; e < 512; e += 256) {
    int j = e >> 5, c = e & 31;
    float ar = 0.f, ai = 0.f;
    for (int o = 0; o < 32; ++o) {
      float wr_ = w1r[j*32+o], wi_ = w1i[j*32+o];
      float fr  = wfr[o*32+c], fi_ = wfi[o*32+c];
      ar += wr_*fr - wi_*fi_;
      ai += wr_*fi_ + wi_*fr;
    }
    W1xr[c*16+j] = ar;  W1xi[c*16+j] = ai;
    w1rt[c*16+j] = w1r[j*32+c];
    w1it[c*16+j] = w1i[j*32+c];
  }
  if (tid < 16) {
    int j = tid;
    float ar = b1r[j], ai = b1i[j];
    for (int o = 0; o < 32; ++o) {
      ar += w1r[j*32+o]*bfr[o] - w1i[j*32+o]*bfi[o];
      ai += w1r[j*32+o]*bfi[o] + w1i[j*32+o]*bfr[o];
    }
    b1pr[j] = ar; b1pi[j] = ai;
  }
}

// ---------------- K12: fused forward partial DFT along z then y ----------------
// grid 4096 = (b*32+c)*64 + x ; x[bc][x][y][z] -> T2[bc][x][ky][kz] (cplx)
__global__ __launch_bounds__(256) void k12_fwd(const float* __restrict__ x, float* __restrict__ T2) {
  __shared__ float plane[64*68];            // [z][y], pad 68 keeps b128 aligned
  __shared__ float2 slab[64*17];            // [y][kz] complex, pad 17
  int blk = blockIdx.x;
  const float* src = x + (size_t)blk * 4096;
  int tid = threadIdx.x;
  for (int i = tid; i < 4096; i += 256) {
    int y = i >> 6, z = i & 63;
    plane[z*68 + y] = src[i];
  }
  __syncthreads();
  // stage 1: z-DFT, thread = (kz, 4 consecutive y)
  {
    int kz = tid & 15, yq = tid >> 4;
    float f = (float)(kz < 8 ? kz : kz - 16);
    float ang = -PI2 * f / 64.0f;
    float sw, cw; __sincosf(ang, &sw, &cw);
    float tr = 1.f, ti = 0.f;
    float a0r=0,a0i=0,a1r=0,a1i=0,a2r=0,a2i=0,a3r=0,a3i=0;
    for (int z = 0; z < 64; ++z) {
      float4 xv = *(const float4*)&plane[z*68 + 4*yq];
      a0r += xv.x*tr; a0i += xv.x*ti;
      a1r += xv.y*tr; a1i += xv.y*ti;
      a2r += xv.z*tr; a2i += xv.z*ti;
      a3r += xv.w*tr; a3i += xv.w*ti;
      float nt = tr*cw - ti*sw; ti = tr*sw + ti*cw; tr = nt;
    }
    int y0 = 4*yq;
    slab[(y0+0)*17 + kz] = make_float2(a0r, a0i);
    slab[(y0+1)*17 + kz] = make_float2(a1r, a1i);
    slab[(y0+2)*17 + kz] = make_float2(a2r, a2i);
    slab[(y0+3)*17 + kz] = make_float2(a3r, a3i);
  }
  __syncthreads();
  // stage 2: y-DFT, thread = (ky, kz)
  {
    int kz = tid & 15, kyi = tid >> 4;
    float f = (float)(kyi < 8 ? kyi : kyi - 16);
    float ang = -PI2 * f / 64.0f;
    float sw, cw; __sincosf(ang, &sw, &cw);
    float tr=1.f, ti=0.f, ar=0.f, ai=0.f;
    for (int y = 0; y < 64; ++y) {
      float2 v = slab[y*17 + kz];
      ar += v.x*tr - v.y*ti;
      ai += v.x*ti + v.y*tr;
      float nt = tr*cw - ti*sw; ti = tr*sw + ti*cw; tr = nt;
    }
    *(float2*)&T2[(size_t)blk*512 + (kyi*16 + kz)*2] = make_float2(ar, ai);
  }
}

// ---------------- K3: forward partial DFT along x ----------------
// grid 1024 = bc*16 + ky ; T2[bc][x][ky][kz] -> xs[bc][m], m=(kx*16+ky)*16+kz
__global__ __launch_bounds__(256) void k3_dftx(const float* __restrict__ T2, float* __restrict__ xs) {
  __shared__ float slab[2048];               // [x][kz] cplx for fixed ky
  int blk = blockIdx.x;
  int bc = blk >> 4, ky = blk & 15;
  int tid = threadIdx.x;
  for (int i = tid; i < 2048; i += 256) {
    int xr = i >> 5, rem = i & 31;
    slab[i] = T2[((size_t)(bc*64 + xr)*16 + ky)*32 + rem];
  }
  __syncthreads();
  int kz = tid & 15, kxi = tid >> 4;
  float f = (float)(kxi < 8 ? kxi : kxi - 16);
  float ang = -PI2 * f / 64.0f;
  float sw, cw; __sincosf(ang, &sw, &cw);
  float tr=1.f, ti=0.f, ar=0.f, ai=0.f;
  for (int xr = 0; xr < 64; ++xr) {
    float2 v = *(const float2*)&slab[(xr*16 + kz)*2];
    ar += v.x*tr - v.y*ti;
    ai += v.x*ti + v.y*tr;
    float nt = tr*cw - ti*sw; ti = tr*sw + ti*cw; tr = nt;
  }
  *(float2*)&xs[(size_t)bc*8192 + (kxi*256 + ky*16 + kz)*2] = make_float2(ar, ai);
}

// ---------------- K4: project onto (shell, harmonic) basis ----------------
// grid 1024 = bc*16 + shell ; coeffs[bc][s][l] = w[s] * sum_{m in shell} xs[m]*Y[l][m]
__global__ __launch_bounds__(256) void k4_proj(const float* __restrict__ xs, const float* __restrict__ Y,
    const int* __restrict__ order, const int* __restrict__ sstart, const float* __restrict__ wsh,
    float* __restrict__ coeffs) {
  int blk = blockIdx.x; int bc = blk >> 4, s = blk & 15;
  int tid = threadIdx.x;
  int st = sstart[s], en = sstart[s+1];
  float ar[9], ai[9];
  #pragma unroll
  for (int l = 0; l < 9; ++l) { ar[l] = 0.f; ai[l] = 0.f; }
  for (int ii = st + tid; ii < en; ii += 256) {
    int m = order[ii];
    float2 v = *(const float2*)&xs[(size_t)bc*8192 + m*2];
    #pragma unroll
    for (int l = 0; l < 9; ++l) {
      float yv = Y[l*4096 + m];
      ar[l] += yv * v.x; ai[l] += yv * v.y;
    }
  }
  __shared__ float red[256*19];
  #pragma unroll
  for (int l = 0; l < 9; ++l) { red[tid*19 + l] = ar[l]; red[tid*19 + 9 + l] = ai[l]; }
  __syncthreads();
  for (int r = 128; r >= 1; r >>= 1) {
    if (tid < r) {
      #pragma unroll
      for (int q = 0; q < 18; ++q) red[tid*19 + q] += red[(tid + r)*19 + q];
    }
    __syncthreads();
  }
  if (tid == 0) {
    float w = wsh[s];
    for (int l = 0; l < 9; ++l) {
      coeffs[((size_t)bc*144 + s*9 + l)*2]     = w * red[l];
      coeffs[((size_t)bc*144 + s*9 + l)*2 + 1] = w * red[9 + l];
    }
  }
}

// ---------------- K5: complex spectral conv + ifft normalization ----------------
// grid 288 = b*144 + (s*9+l) ; coeffs2[b][o][sl] = (1/64^3) * sum_i coeffs[b][i][sl]*wspec[sl][i][o]
__global__ __launch_bounds__(64) void k5_spec(const float* __restrict__ coeffs,
    const float* __restrict__ wsr, const float* __restrict__ wsi, float* __restrict__ coeffs2) {
  int blk = blockIdx.x;
  int b = blk / 144, sl = blk % 144;
  int o = threadIdx.x;
  if (o >= 32) return;
  float ar = 0.f, ai = 0.f;
  for (int i = 0; i < 32; ++i) {
    float cr = coeffs[((size_t)(b*32 + i)*144 + sl)*2];
    float ci = coeffs[((size_t)(b*32 + i)*144 + sl)*2 + 1];
    float wr = wsr[(sl*32 + i)*32 + o];
    float wi = wsi[(sl*32 + i)*32 + o];
    ar += cr*wr - ci*wi;
    ai += cr*wi + ci*wr;
  }
  const float sc = 1.0f / 262144.0f;
  coeffs2[((size_t)(b*32 + o)*144 + sl)*2]     = ar * sc;
  coeffs2[((size_t)(b*32 + o)*144 + sl)*2 + 1] = ai * sc;
}

// ---------------- K7: back-project to modes ----------------
// grid 1024 = bo*16 + chunk ; xs2[bo][m] = w[sh(m)] * sum_l coeffs2[bo][sh*9+l]*Y[l][m]
__global__ __launch_bounds__(256) void k7_unproj(const float* __restrict__ coeffs2, const float* __restrict__ Y,
    const int* __restrict__ shellOf, const float* __restrict__ wsh, float* __restrict__ xs2) {
  int bo = blockIdx.x >> 4;
  int m = ((blockIdx.x & 15) << 8) | threadIdx.x;
  __shared__ float c2[288];
  for (int i = threadIdx.x; i < 288; i += 256) c2[i] = coeffs2[(size_t)bo*288 + i];
  __syncthreads();
  int sh = shellOf[m];
  float w = wsh[sh];
  float ar = 0.f, ai = 0.f;
  #pragma unroll
  for (int l = 0; l < 9; ++l) {
    float yv = Y[l*4096 + m];
    ar += yv * c2[(sh*9 + l)*2];
    ai += yv * c2[(sh*9 + l)*2 + 1];
  }
  xs2[(size_t)bo*8192 + m*2]     = w * ar;
  xs2[(size_t)bo*8192 + m*2 + 1] = w * ai;
}

// ---------------- K8: inverse partial DFT along x ----------------
// grid 1024 = bo*16 + ky ; xs2[bo][m] -> U1[bo][x][ky][kz]
__global__ __launch_bounds__(256) void k8_invx(const float* __restrict__ xs2, float* __restrict__ U1) {
  __shared__ float slab[512];                 // [kx][kz] cplx for fixed ky
  int blk = blockIdx.x;
  int bo = blk >> 4, ky = blk & 15;
  int tid = threadIdx.x;
  for (int i = tid; i < 512; i += 256) {
    int kx = i >> 5, rem = i & 31;
    slab[i] = xs2[(size_t)bo*8192 + kx*512 + ky*32 + rem];
  }
  __syncthreads();
  int kz = tid & 15, grp = tid >> 4;          // outputs x = grp + 16q
  float tr4[4], ti4[4], wr4[4], wi4[4], ar4[4], ai4[4];
  #pragma unroll
  for (int q = 0; q < 4; ++q) {
    int xx = grp + 16*q;
    float ang = PI2 * (float)xx / 64.0f;
    __sincosf(ang, &wi4[q], &wr4[q]);
    tr4[q] = 1.f; ti4[q] = 0.f; ar4[q] = 0.f; ai4[q] = 0.f;
  }
  #pragma unroll
  for (int kx = 0; kx < 16; ++kx) {
    if (kx == 8) { ti4[0] = -ti4[0]; ti4[1] = -ti4[1]; ti4[2] = -ti4[2]; ti4[3] = -ti4[3]; }
    float2 v = *(const float2*)&slab[(kx*16 + kz)*2];
    #pragma unroll
    for (int q = 0; q < 4; ++q) {
      ar4[q] += v.x*tr4[q] - v.y*ti4[q];
      ai4[q] += v.x*ti4[q] + v.y*tr4[q];
      float nt = tr4[q]*wr4[q] - ti4[q]*wi4[q];
      ti4[q] = tr4[q]*wi4[q] + ti4[q]*wr4[q];
      tr4[q] = nt;
    }
  }
  #pragma unroll
  for (int q = 0; q < 4; ++q) {
    int xx = grp + 16*q;
    *(float2*)&U1[((size_t)(bo*64 + xx)*16 + ky)*32 + kz*2] = make_float2(ar4[q], ai4[q]);
  }
}

// ---------------- K9: inverse partial DFT along y ----------------
// grid 4096 = bo*64 + x ; U1[bo][x][ky][kz] -> U2[bo][x][y][kz]
__global__ __launch_bounds__(256) void k9_invy(const float* __restrict__ U1, float* __restrict__ U2) {
  __shared__ float slab[512];
  int blk = blockIdx.x;
  int tid = threadIdx.x;
  const float* src = U1 + (size_t)blk * 512;
  for (int i = tid; i < 512; i += 256) slab[i] = src[i];
  __syncthreads();
  int kz = tid & 15, grp = tid >> 4;
  float tr4[4], ti4[4], wr4[4], wi4[4], ar4[4], ai4[4];
  #pragma unroll
  for (int q = 0; q < 4; ++q) {
    int yy = grp + 16*q;
    float ang = PI2 * (float)yy / 64.0f;
    __sincosf(ang, &wi4[q], &wr4[q]);
    tr4[q] = 1.f; ti4[q] = 0.f; ar4[q] = 0.f; ai4[q] = 0.f;
  }
  #pragma unroll
  for (int ky = 0; ky < 16; ++ky) {
    if (ky == 8) { ti4[0] = -ti4[0]; ti4[1] = -ti4[1]; ti4[2] = -ti4[2]; ti4[3] = -ti4[3]; }
    float2 v = *(const float2*)&slab[(ky*16 + kz)*2];
    #pragma unroll
    for (int q = 0; q < 4; ++q) {
      ar4[q] += v.x*tr4[q] - v.y*ti4[q];
      ai4[q] += v.x*ti4[q] + v.y*tr4[q];
      float nt = tr4[q]*wr4[q] - ti4[q]*wi4[q];
      ti4[q] = tr4[q]*wi4[q] + ti4[q]*wr4[q];
      tr4[q] = nt;
    }
  }
  float* dst = U2 + (size_t)blk * 2048;
  #pragma unroll
  for (int q = 0; q < 4; ++q) {
    int yy = grp + 16*q;
    *(float2*)&dst[(yy*16 + kz)*2] = make_float2(ar4[q], ai4[q]);
  }
}

// ---------------- K10: inverse-z DFT + MLP + skips, fused epilogue ----------------
// grid 2048 = (b*64 + x)*16 + yblock(4 y-lines) ; 256 threads
__global__ __launch_bounds__(256) void k10_final(
    const float* __restrict__ x, const float* __restrict__ U2,
    const float* __restrict__ ws,
    const float* __restrict__ w2r, const float* __restrict__ w2i,
    const float* __restrict__ b2r, const float* __restrict__ wgr,
    float* __restrict__ out) {
  const float* w1rt = ws + O_W1RT;  const float* w1it = ws + O_W1IT;
  const float* W1xr = ws + O_W1XR;  const float* W1xi = ws + O_W1XI;
  const float* b1pr = ws + O_B1PR;  const float* b1pi = ws + O_B1PI;

  __shared__ __hip_bfloat16 xline[4*32*64];   // [y][c][z], 16384 B
  __shared__ unsigned int xf[4*32*65];        // packed bf16 (re lo16, im hi16), stride 65 -> 33280 B
  float* scratch = (float*)xf;                // U2 staging, aliased (4*32*34 = 4352 floats)

  int tid = threadIdx.x;
  int blk = blockIdx.x;
  int yb = blk & 15, bx = blk >> 4;
  int b = bx >> 6, xr = bx & 63;
  int y0 = yb * 4;

  // Phase 1: cooperative coalesced loads: x -> xline, U2 chunk -> scratch
  for (int i = tid; i < 8192; i += 256) {
    int y = i >> 11, c = (i >> 6) & 31, z = i & 63;
    float v = x[(size_t)(b*32 + c)*262144 + (size_t)xr*4096 + (size_t)(y0 + y)*64 + z];
    xline[(y*32 + c)*64 + z] = __float2bfloat16(v);
  }
  for (int e = tid; e < 2048; e += 256) {
    int q = e & 15, o = (e >> 4) & 31, ya = e >> 9;
    size_t gbase = (((size_t)(b*32 + o)*64 + xr)*64 + (size_t)(y0 + ya))*32;
    float2 v = *(const float2*)&U2[gbase + q*2];
    *(float2*)&scratch[(ya*32 + o)*34 + q*2] = v;   // stride 34: (2o+2q)%32, 2-way max (free)
  }
  __syncthreads();

  // Phase 2: per-thread read of its o-slice, then inverse-z DFT into packed xf
  {
    int o = tid & 31, g = tid >> 5;
    int ya = g >> 1, zh = g & 1;
    float ur[16], ui[16];
    const float2* sp = (const float2*)&scratch[(ya*32 + o)*34];
    #pragma unroll
    for (int q = 0; q < 16; ++q) { float2 v = sp[q]; ur[q] = v.x; ui[q] = v.y; }
    __syncthreads();   // scratch fully consumed; xf region may now be overwritten

    for (int zz = 0; zz < 16; ++zz) {
      int z = zh*16 + zz;
      float ang = PI2 * (float)z / 64.0f;
      float sw, cw; __sincosf(ang, &sw, &cw);
      float tr = 1.f, ti = 0.f;
      float er = 0.f, ei = 0.f, odr = 0.f, odi = 0.f;
      #pragma unroll
      for (int kz = 0; kz < 16; ++kz) {
        if (kz == 8) ti = -ti;                 // f jumps from +8 to -8: conjugate
        float pr  = ur[kz]*tr - ui[kz]*ti;
        float pi_ = ur[kz]*ti + ui[kz]*tr;
        if (kz & 1) { odr += pr; odi += pi_; } else { er += pr; ei += pi_; }
        float nt = tr*cw - ti*sw; ti = tr*sw + ti*cw; tr = nt;
      }
      int c0 = (ya*32 + o)*65;
      xf[c0 + z]      = f2bfbits(er + odr) | (f2bfbits(ei + odi) << 16);
      xf[c0 + z + 32] = f2bfbits(er - odr) | (f2bfbits(ei - odi) << 16);
    }
  }
  __syncthreads();

  // Phase 3: per point: h = gelu(w1@x_fno + W1x@x + b1'); out = Re(w2@h)+b2r + x*w_gate_r
  {
    int z = tid & 63, ya = tid >> 6;
    float hr[16], hi[16];
    #pragma unroll
    for (int j = 0; j < 16; ++j) { hr[j] = b1pr[j]; hi[j] = b1pi[j]; }
    for (int c = 0; c < 32; ++c) {
      int c0 = ya*32 + c;
      unsigned int pk = xf[c0*65 + z];
      float fr = __uint_as_float(pk << 16);
      float fi = __uint_as_float(pk & 0xffff0000u);
      float xv = __bfloat162float(xline[c0*64 + z]);
      const float* w1r_c = w1rt + c*16;
      const float* w1i_c = w1it + c*16;
      const float* Wr_c  = W1xr + c*16;
      const float* Wi_c  = W1xi + c*16;
      #pragma unroll
      for (int j = 0; j < 16; ++j) {
        hr[j] += w1r_c[j]*fr - w1i_c[j]*fi + Wr_c[j]*xv;
        hi[j] += w1r_c[j]*fi + w1i_c[j]*fr + Wi_c[j]*xv;
      }
    }
    #pragma unroll
    for (int j = 0; j < 16; ++j) { hr[j] = geluf(hr[j]); hi[j] = geluf(hi[j]); }
    for (int o = 0; o < 32; ++o) {
      const float* w2r_o = w2r + o*16;
      const float* w2i_o = w2i + o*16;
      float acc = b2r[o];
      #pragma unroll
      for (int j = 0; j < 16; ++j) acc += w2r_o[j]*hr[j] - w2i_o[j]*hi[j];
      float xv = __bfloat162float(xline[(ya*32 + o)*64 + z]);
      out[(size_t)(b*32 + o)*262144 + (size_t)xr*4096 + (size_t)(y0 + ya)*64 + z] = acc + xv*wgr[o];
    }
  }
}

// ---------------- launch ----------------
extern "C" void kernel_launch(void* const* d_in, const int* in_sizes, int n_in,
                              void* d_out, int out_size, void* d_ws, size_t ws_size,
                              hipStream_t stream) {
  (void)in_sizes; (void)n_in; (void)out_size; (void)ws_size;
  const float* x   = (const float*)d_in[0];
  const float* wfr = (const float*)d_in[1];
  const float* wfi = (const float*)d_in[2];
  const float* bfr = (const float*)d_in[3];
  const float* bfi = (const float*)d_in[4];
  const float* wgr = (const float*)d_in[5];
  const float* wsr = (const float*)d_in[7];
  const float* wsi = (const float*)d_in[8];
  const float* w1r = (const float*)d_in[9];
  const float* w1i = (const float*)d_in[10];
  const float* b1r = (const float*)d_in[11];
  const float* b1i = (const float*)d_in[12];
  const float* w2r = (const float*)d_in[13];
  const float* w2i = (const float*)d_in[14];
  const float* b2r = (const float*)d_in[15];
  float* out = (float*)d_out;
  float* ws  = (float*)d_ws;

  float* T1      = ws + O_T1;    // U2 home
  float* T2      = ws + O_T2;    // also U1
  float* xs      = ws + O_XS;
  float* xs2     = ws + O_XS2;
  float* coeffs  = ws + O_COEF;
  float* coeffs2 = ws + O_COEF2;
  float* Y       = ws + O_Y;
  int* shellOf   = (int*)(ws + O_SHELL);
  int* order     = (int*)(ws + O_ORDER);
  int* sstart    = (int*)(ws + O_SSTART);
  float* wsh     = ws + O_WSH;

  hipLaunchKernelGGL(k0_init,  dim3(1),    dim3(256), 0, stream, wfr, wfi, bfr, bfi, w1r, w1i, b1r, b1i, ws);
  hipLaunchKernelGGL(k12_fwd,  dim3(4096), dim3(256), 0, stream, x, T2);
  hipLaunchKernelGGL(k3_dftx,  dim3(1024), dim3(256), 0, stream, T2, xs);
  hipLaunchKernelGGL(k4_proj,  dim3(1024), dim3(256), 0, stream, xs, Y, order, sstart, wsh, coeffs);
  hipLaunchKernelGGL(k5_spec,  dim3(288),  dim3(64),  0, stream, coeffs, wsr, wsi, coeffs2);
  hipLaunchKernelGGL(k7_unproj,dim3(1024), dim3(256), 0, stream, coeffs2, Y, shellOf, wsh, xs2);
  hipLaunchKernelGGL(k8_invx,  dim3(1024), dim3(256), 0, stream, xs2, T2);
  hipLaunchKernelGGL(k9_invy,  dim3(4096), dim3(256), 0, stream, T2, T1);
  hipLaunchKernelGGL(k10_final,dim3(2048), dim3(256), 0, stream, x, T1, ws, w2r, w2i, b2r, wgr, out);
}

// Round 3
// 311.392 us; speedup vs baseline: 1.2207x; 1.1283x over previous
//
#include <hip/hip_runtime.h>
#include <hip/hip_bf16.h>

#define PI2 6.283185307179586f

typedef __attribute__((ext_vector_type(8))) short short8;
typedef __attribute__((ext_vector_type(4))) float f32x4;

// ---------------- workspace layout (float offsets) ----------------
static const size_t O_Y      = 0;          // 9*4096 harmonics
static const size_t O_W1RT   = 36864;      // 512  w1 real, transposed [c][j]
static const size_t O_W1IT   = 37376;      // 512
static const size_t O_W1XR   = 37888;      // 512  (w1 @ w_fno) real [c][j]
static const size_t O_W1XI   = 38400;      // 512
static const size_t O_B1PR   = 38912;      // 16   w1@b_fno + b1
static const size_t O_B1PI   = 38928;      // 16
static const size_t O_WSH    = 38944;      // 16   1/sqrt(cnt)
static const size_t O_SHELL  = 38960;      // int[4096]
static const size_t O_ORDER  = 43056;      // int[4096]
static const size_t O_SSTART = 47152;      // int[32]
static const size_t O_COEF   = 47232;      // 2*32*144*2
static const size_t O_COEF2  = 65664;      // 2*32*144*2
static const size_t O_XS     = 84096;      // 2*32*4096*2
static const size_t O_XS2    = 608384;     // 2*32*4096*2
static const size_t O_T2     = 1132672;    // 2*32*64*16*16*2  (reused as U1)
static const size_t O_T1     = 3229824;    // 2*32*64*64*16*2  (reused as U2)
// total 11618432 floats = 46.5 MB

static __device__ __forceinline__ float geluf(float v) {
  // tanh-approx gelu (jax.nn.gelu approximate=True)
  float u = 0.7978845608028654f * (v + 0.044715f * v * v * v);
  float a = fabsf(u);
  float e = __expf(-2.0f * a);
  float th = (1.0f - e) / (1.0f + e);
  th = copysignf(th, u);
  return 0.5f * v * (1.0f + th);
}

static __device__ __forceinline__ unsigned int f2bfbits(float f) {
  // RNE f32 -> bf16 bits
  unsigned int u = __float_as_uint(f);
  u += 0x7fffu + ((u >> 16) & 1u);
  return u >> 16;
}

static __device__ __forceinline__ unsigned int pk2(float a, float b) {
  return f2bfbits(a) | (f2bfbits(b) << 16);
}

// ---------------- K0: tables + folded weights (1 block) ----------------
__global__ __launch_bounds__(256) void k0_init(
    const float* __restrict__ wfr, const float* __restrict__ wfi,
    const float* __restrict__ bfr, const float* __restrict__ bfi,
    const float* __restrict__ w1r, const float* __restrict__ w1i,
    const float* __restrict__ b1r, const float* __restrict__ b1i,
    float* __restrict__ ws) {
  float* Y    = ws + O_Y;
  float* w1rt = ws + O_W1RT;  float* w1it = ws + O_W1IT;
  float* W1xr = ws + O_W1XR;  float* W1xi = ws + O_W1XI;
  float* b1pr = ws + O_B1PR;  float* b1pi = ws + O_B1PI;
  float* wsh  = ws + O_WSH;
  int* shellOf = (int*)(ws + O_SHELL);
  int* order   = (int*)(ws + O_ORDER);
  int* sstart  = (int*)(ws + O_SSTART);

  __shared__ int cnt[16], fill[16], st[17];
  int tid = threadIdx.x;
  if (tid < 16) { cnt[tid] = 0; fill[tid] = 0; }
  __syncthreads();
  for (int m = tid; m < 4096; m += 256) {
    int ix = m >> 8, iy = (m >> 4) & 15, iz = m & 15;
    float kx = (float)(ix < 8 ? ix : ix - 16);
    float ky = (float)(iy < 8 ? iy : iy - 16);
    float kz = (float)(iz < 8 ? iz : iz - 16);
    float r2 = kx*kx + ky*ky + kz*kz;
    float r  = sqrtf(r2);
    float nzm = r2 > 0.f ? 1.f : 0.f;
    float inv = r2 > 0.f ? 1.0f / fmaxf(r, 1e-9f) : 0.f;
    float ux = kx*inv, uy = ky*inv, uz = kz*inv;
    Y[0*4096+m] = 0.282095f;
    Y[1*4096+m] = 0.488603f * uy;
    Y[2*4096+m] = 0.488603f * uz;
    Y[3*4096+m] = 0.488603f * ux;
    Y[4*4096+m] = 1.092548f * ux*uy;
    Y[5*4096+m] = 1.092548f * uy*uz;
    Y[6*4096+m] = 0.315392f * (3.0f*uz*uz - nzm);
    Y[7*4096+m] = 1.092548f * ux*uz;
    Y[8*4096+m] = 0.546274f * (ux*ux - uy*uy);
    float rmax = sqrtf(192.0f);
    float t = r / (rmax + 1e-6f) * 16.0f;
    int sh = (int)t; sh = sh > 15 ? 15 : sh;
    shellOf[m] = sh;
    atomicAdd(&cnt[sh], 1);
  }
  __syncthreads();
  if (tid == 0) { int a = 0; for (int s = 0; s < 16; ++s) { st[s] = a; a += cnt[s]; } st[16] = a; }
  __syncthreads();
  if (tid < 16) wsh[tid] = 1.0f / sqrtf(fmaxf((float)cnt[tid], 1.0f));
  if (tid < 17) sstart[tid] = st[tid];
  for (int m = tid; m < 4096; m += 256) {
    int sh = shellOf[m];
    int p = atomicAdd(&fill[sh], 1);
    order[st[sh] + p] = m;
  }
  for (int e = tid; e < 512; e += 256) {
    int j = e >> 5, c = e & 31;
    float ar = 0.f, ai = 0.f;
    for (int o = 0; o < 32; ++o) {
      float wr_ = w1r[j*32+o], wi_ = w1i[j*32+o];
      float fr  = wfr[o*32+c], fi_ = wfi[o*32+c];
      ar += wr_*fr - wi_*fi_;
      ai += wr_*fi_ + wi_*fr;
    }
    W1xr[c*16+j] = ar;  W1xi[c*16+j] = ai;
    w1rt[c*16+j] = w1r[j*32+c];
    w1it[c*16+j] = w1i[j*32+c];
  }
  if (tid < 16) {
    int j = tid;
    float ar = b1r[j], ai = b1i[j];
    for (int o = 0; o < 32; ++o) {
      ar += w1r[j*32+o]*bfr[o] - w1i[j*32+o]*bfi[o];
      ai += w1r[j*32+o]*bfi[o] + w1i[j*32+o]*bfr[o];
    }
    b1pr[j] = ar; b1pi[j] = ai;
  }
}

// ---------------- K12: fused forward partial DFT along z then y ----------------
__global__ __launch_bounds__(256) void k12_fwd(const float* __restrict__ x, float* __restrict__ T2) {
  __shared__ float plane[64*68];
  __shared__ float2 slab[64*17];
  int blk = blockIdx.x;
  const float* src = x + (size_t)blk * 4096;
  int tid = threadIdx.x;
  for (int i = tid; i < 4096; i += 256) {
    int y = i >> 6, z = i & 63;
    plane[z*68 + y] = src[i];
  }
  __syncthreads();
  {
    int kz = tid & 15, yq = tid >> 4;
    float f = (float)(kz < 8 ? kz : kz - 16);
    float ang = -PI2 * f / 64.0f;
    float sw, cw; __sincosf(ang, &sw, &cw);
    float tr = 1.f, ti = 0.f;
    float a0r=0,a0i=0,a1r=0,a1i=0,a2r=0,a2i=0,a3r=0,a3i=0;
    for (int z = 0; z < 64; ++z) {
      float4 xv = *(const float4*)&plane[z*68 + 4*yq];
      a0r += xv.x*tr; a0i += xv.x*ti;
      a1r += xv.y*tr; a1i += xv.y*ti;
      a2r += xv.z*tr; a2i += xv.z*ti;
      a3r += xv.w*tr; a3i += xv.w*ti;
      float nt = tr*cw - ti*sw; ti = tr*sw + ti*cw; tr = nt;
    }
    int y0 = 4*yq;
    slab[(y0+0)*17 + kz] = make_float2(a0r, a0i);
    slab[(y0+1)*17 + kz] = make_float2(a1r, a1i);
    slab[(y0+2)*17 + kz] = make_float2(a2r, a2i);
    slab[(y0+3)*17 + kz] = make_float2(a3r, a3i);
  }
  __syncthreads();
  {
    int kz = tid & 15, kyi = tid >> 4;
    float f = (float)(kyi < 8 ? kyi : kyi - 16);
    float ang = -PI2 * f / 64.0f;
    float sw, cw; __sincosf(ang, &sw, &cw);
    float tr=1.f, ti=0.f, ar=0.f, ai=0.f;
    for (int y = 0; y < 64; ++y) {
      float2 v = slab[y*17 + kz];
      ar += v.x*tr - v.y*ti;
      ai += v.x*ti + v.y*tr;
      float nt = tr*cw - ti*sw; ti = tr*sw + ti*cw; tr = nt;
    }
    *(float2*)&T2[(size_t)blk*512 + (kyi*16 + kz)*2] = make_float2(ar, ai);
  }
}

// ---------------- K3: forward partial DFT along x ----------------
__global__ __launch_bounds__(256) void k3_dftx(const float* __restrict__ T2, float* __restrict__ xs) {
  __shared__ float slab[2048];
  int blk = blockIdx.x;
  int bc = blk >> 4, ky = blk & 15;
  int tid = threadIdx.x;
  for (int i = tid; i < 2048; i += 256) {
    int xr = i >> 5, rem = i & 31;
    slab[i] = T2[((size_t)(bc*64 + xr)*16 + ky)*32 + rem];
  }
  __syncthreads();
  int kz = tid & 15, kxi = tid >> 4;
  float f = (float)(kxi < 8 ? kxi : kxi - 16);
  float ang = -PI2 * f / 64.0f;
  float sw, cw; __sincosf(ang, &sw, &cw);
  float tr=1.f, ti=0.f, ar=0.f, ai=0.f;
  for (int xr = 0; xr < 64; ++xr) {
    float2 v = *(const float2*)&slab[(xr*16 + kz)*2];
    ar += v.x*tr - v.y*ti;
    ai += v.x*ti + v.y*tr;
    float nt = tr*cw - ti*sw; ti = tr*sw + ti*cw; tr = nt;
  }
  *(float2*)&xs[(size_t)bc*8192 + (kxi*256 + ky*16 + kz)*2] = make_float2(ar, ai);
}

// ---------------- K4: project onto (shell, harmonic) basis ----------------
__global__ __launch_bounds__(256) void k4_proj(const float* __restrict__ xs, const float* __restrict__ Y,
    const int* __restrict__ order, const int* __restrict__ sstart, const float* __restrict__ wsh,
    float* __restrict__ coeffs) {
  int blk = blockIdx.x; int bc = blk >> 4, s = blk & 15;
  int tid = threadIdx.x;
  int st = sstart[s], en = sstart[s+1];
  float ar[9], ai[9];
  #pragma unroll
  for (int l = 0; l < 9; ++l) { ar[l] = 0.f; ai[l] = 0.f; }
  for (int ii = st + tid; ii < en; ii += 256) {
    int m = order[ii];
    float2 v = *(const float2*)&xs[(size_t)bc*8192 + m*2];
    #pragma unroll
    for (int l = 0; l < 9; ++l) {
      float yv = Y[l*4096 + m];
      ar[l] += yv * v.x; ai[l] += yv * v.y;
    }
  }
  __shared__ float red[256*19];
  #pragma unroll
  for (int l = 0; l < 9; ++l) { red[tid*19 + l] = ar[l]; red[tid*19 + 9 + l] = ai[l]; }
  __syncthreads();
  for (int r = 128; r >= 1; r >>= 1) {
    if (tid < r) {
      #pragma unroll
      for (int q = 0; q < 18; ++q) red[tid*19 + q] += red[(tid + r)*19 + q];
    }
    __syncthreads();
  }
  if (tid == 0) {
    float w = wsh[s];
    for (int l = 0; l < 9; ++l) {
      coeffs[((size_t)bc*144 + s*9 + l)*2]     = w * red[l];
      coeffs[((size_t)bc*144 + s*9 + l)*2 + 1] = w * red[9 + l];
    }
  }
}

// ---------------- K5: complex spectral conv + ifft normalization ----------------
__global__ __launch_bounds__(64) void k5_spec(const float* __restrict__ coeffs,
    const float* __restrict__ wsr, const float* __restrict__ wsi, float* __restrict__ coeffs2) {
  int blk = blockIdx.x;
  int b = blk / 144, sl = blk % 144;
  int o = threadIdx.x;
  if (o >= 32) return;
  float ar = 0.f, ai = 0.f;
  for (int i = 0; i < 32; ++i) {
    float cr = coeffs[((size_t)(b*32 + i)*144 + sl)*2];
    float ci = coeffs[((size_t)(b*32 + i)*144 + sl)*2 + 1];
    float wr = wsr[(sl*32 + i)*32 + o];
    float wi = wsi[(sl*32 + i)*32 + o];
    ar += cr*wr - ci*wi;
    ai += cr*wi + ci*wr;
  }
  const float sc = 1.0f / 262144.0f;
  coeffs2[((size_t)(b*32 + o)*144 + sl)*2]     = ar * sc;
  coeffs2[((size_t)(b*32 + o)*144 + sl)*2 + 1] = ai * sc;
}

// ---------------- K7: back-project to modes ----------------
__global__ __launch_bounds__(256) void k7_unproj(const float* __restrict__ coeffs2, const float* __restrict__ Y,
    const int* __restrict__ shellOf, const float* __restrict__ wsh, float* __restrict__ xs2) {
  int bo = blockIdx.x >> 4;
  int m = ((blockIdx.x & 15) << 8) | threadIdx.x;
  __shared__ float c2[288];
  for (int i = threadIdx.x; i < 288; i += 256) c2[i] = coeffs2[(size_t)bo*288 + i];
  __syncthreads();
  int sh = shellOf[m];
  float w = wsh[sh];
  float ar = 0.f, ai = 0.f;
  #pragma unroll
  for (int l = 0; l < 9; ++l) {
    float yv = Y[l*4096 + m];
    ar += yv * c2[(sh*9 + l)*2];
    ai += yv * c2[(sh*9 + l)*2 + 1];
  }
  xs2[(size_t)bo*8192 + m*2]     = w * ar;
  xs2[(size_t)bo*8192 + m*2 + 1] = w * ai;
}

// ---------------- K8: inverse partial DFT along x ----------------
__global__ __launch_bounds__(256) void k8_invx(const float* __restrict__ xs2, float* __restrict__ U1) {
  __shared__ float slab[512];
  int blk = blockIdx.x;
  int bo = blk >> 4, ky = blk & 15;
  int tid = threadIdx.x;
  for (int i = tid; i < 512; i += 256) {
    int kx = i >> 5, rem = i & 31;
    slab[i] = xs2[(size_t)bo*8192 + kx*512 + ky*32 + rem];
  }
  __syncthreads();
  int kz = tid & 15, grp = tid >> 4;
  float tr4[4], ti4[4], wr4[4], wi4[4], ar4[4], ai4[4];
  #pragma unroll
  for (int q = 0; q < 4; ++q) {
    int xx = grp + 16*q;
    float ang = PI2 * (float)xx / 64.0f;
    __sincosf(ang, &wi4[q], &wr4[q]);
    tr4[q] = 1.f; ti4[q] = 0.f; ar4[q] = 0.f; ai4[q] = 0.f;
  }
  #pragma unroll
  for (int kx = 0; kx < 16; ++kx) {
    if (kx == 8) { ti4[0] = -ti4[0]; ti4[1] = -ti4[1]; ti4[2] = -ti4[2]; ti4[3] = -ti4[3]; }
    float2 v = *(const float2*)&slab[(kx*16 + kz)*2];
    #pragma unroll
    for (int q = 0; q < 4; ++q) {
      ar4[q] += v.x*tr4[q] - v.y*ti4[q];
      ai4[q] += v.x*ti4[q] + v.y*tr4[q];
      float nt = tr4[q]*wr4[q] - ti4[q]*wi4[q];
      ti4[q] = tr4[q]*wi4[q] + ti4[q]*wr4[q];
      tr4[q] = nt;
    }
  }
  #pragma unroll
  for (int q = 0; q < 4; ++q) {
    int xx = grp + 16*q;
    *(float2*)&U1[((size_t)(bo*64 + xx)*16 + ky)*32 + kz*2] = make_float2(ar4[q], ai4[q]);
  }
}

// ---------------- K9: inverse partial DFT along y ----------------
__global__ __launch_bounds__(256) void k9_invy(const float* __restrict__ U1, float* __restrict__ U2) {
  __shared__ float slab[512];
  int blk = blockIdx.x;
  int tid = threadIdx.x;
  const float* src = U1 + (size_t)blk * 512;
  for (int i = tid; i < 512; i += 256) slab[i] = src[i];
  __syncthreads();
  int kz = tid & 15, grp = tid >> 4;
  float tr4[4], ti4[4], wr4[4], wi4[4], ar4[4], ai4[4];
  #pragma unroll
  for (int q = 0; q < 4; ++q) {
    int yy = grp + 16*q;
    float ang = PI2 * (float)yy / 64.0f;
    __sincosf(ang, &wi4[q], &wr4[q]);
    tr4[q] = 1.f; ti4[q] = 0.f; ar4[q] = 0.f; ai4[q] = 0.f;
  }
  #pragma unroll
  for (int ky = 0; ky < 16; ++ky) {
    if (ky == 8) { ti4[0] = -ti4[0]; ti4[1] = -ti4[1]; ti4[2] = -ti4[2]; ti4[3] = -ti4[3]; }
    float2 v = *(const float2*)&slab[(ky*16 + kz)*2];
    #pragma unroll
    for (int q = 0; q < 4; ++q) {
      ar4[q] += v.x*tr4[q] - v.y*ti4[q];
      ai4[q] += v.x*ti4[q] + v.y*tr4[q];
      float nt = tr4[q]*wr4[q] - ti4[q]*wi4[q];
      ti4[q] = tr4[q]*wi4[q] + ti4[q]*wr4[q];
      tr4[q] = nt;
    }
  }
  float* dst = U2 + (size_t)blk * 2048;
  #pragma unroll
  for (int q = 0; q < 4; ++q) {
    int yy = grp + 16*q;
    *(float2*)&dst[(yy*16 + kz)*2] = make_float2(ar4[q], ai4[q]);
  }
}

// ---------------- K10: inverse-z DFT + MFMA MLP + skips ----------------
// grid 4096 = ((b*64 + x)*32 + yblock) ; 2 y-lines per block, 256 threads
__global__ __launch_bounds__(256) void k10_final(
    const float* __restrict__ x, const float* __restrict__ U2,
    const float* __restrict__ ws,
    const float* __restrict__ w2r, const float* __restrict__ w2i,
    const float* __restrict__ b2r, const float* __restrict__ wgr,
    float* __restrict__ out) {
  const float* w1rt = ws + O_W1RT;  const float* w1it = ws + O_W1IT;
  const float* W1xr = ws + O_W1XR;  const float* W1xi = ws + O_W1XI;
  const float* b1pr = ws + O_B1PR;  const float* b1pi = ws + O_B1PI;

  // rows = 2 ya * 64 z = 128 ; xfT[row*33 + c] packed bf16 {re,im} ; xlT[row*34 + c] bf16
  __shared__ unsigned int xfT[128*33];        // 16896 B (aliased by U2 scratch in phase 1/2)
  __shared__ __hip_bfloat16 xlT[128*34];      // 8704 B
  __shared__ unsigned int hpW[4*272];         // per-wave H buffer: 16 p * 17 words, 4352 B
  float* scratch = (float*)xfT;

  int tid = threadIdx.x;
  int blk = blockIdx.x;
  int yb = blk & 31, bx = blk >> 5;
  int b = bx >> 6, xr = bx & 63;
  int y0 = yb * 2;

  // ---- Phase 1: coalesced staging ----
  for (int i = tid; i < 4096; i += 256) {
    int ya = i >> 11, c = (i >> 6) & 31, z = i & 63;
    float v = x[(size_t)(b*32 + c)*262144 + (size_t)xr*4096 + (size_t)(y0 + ya)*64 + z];
    xlT[((ya << 6) + z)*34 + c] = __float2bfloat16(v);
  }
  for (int e = tid; e < 1024; e += 256) {
    int q = e & 15, o = (e >> 4) & 31, ya = e >> 9;
    const float2* g = (const float2*)(U2 + ((size_t)((b*32 + o)*64 + xr))*2048 + (size_t)(y0 + ya)*32);
    *(float2*)&scratch[(ya*32 + o)*34 + 2*q] = g[q];
  }
  __syncthreads();

  // ---- Phase 2: inverse-z DFT (z/z+32 parity pairing), write packed bf16 xfT ----
  {
    int o = tid & 31, r3 = tid >> 5;
    int ya = r3 >> 2, zq = r3 & 3;
    float ur[16], ui[16];
    const float2* sp = (const float2*)&scratch[(ya*32 + o)*34];
    #pragma unroll
    for (int q = 0; q < 16; ++q) { float2 v = sp[q]; ur[q] = v.x; ui[q] = v.y; }
    __syncthreads();   // scratch consumed; xfT region may be overwritten

    for (int zz = 0; zz < 8; ++zz) {
      int z = zq*8 + zz;
      float ang = PI2 * (float)z / 64.0f;
      float sw, cw; __sincosf(ang, &sw, &cw);
      float tr = 1.f, ti = 0.f;
      float er = 0.f, ei = 0.f, odr = 0.f, odi = 0.f;
      #pragma unroll
      for (int kz = 0; kz < 16; ++kz) {
        if (kz == 8) ti = -ti;
        float pr  = ur[kz]*tr - ui[kz]*ti;
        float pi_ = ur[kz]*ti + ui[kz]*tr;
        if (kz & 1) { odr += pr; odi += pi_; } else { er += pr; ei += pi_; }
        float nt = tr*cw - ti*sw; ti = tr*sw + ti*cw; tr = nt;
      }
      int row0 = (ya << 6) + z;
      xfT[row0*33 + o]        = pk2(er + odr, ei + odi);
      xfT[(row0 + 32)*33 + o] = pk2(er - odr, ei - odi);
    }
  }
  __syncthreads();

  // ---- Phase 3: MFMA channel-mix MLP ----
  {
    int lane = tid & 63, wv = tid >> 6;
    int p = lane & 15, q = lane >> 4;
    int wb = wv * 272;

    union U8 { short8 v; unsigned int u[4]; };
    // A-fragments: A[m=lane&15][k=quad*8+j]
    U8 fW1r, fW1i, fW1iN, fW1xr, fW1xi, fW2[2];
    #pragma unroll
    for (int s = 0; s < 4; ++s) {
      int c0 = 8*q + 2*s, c1 = c0 + 1;
      fW1r.u[s]  = pk2(w1rt[c0*16 + p], w1rt[c1*16 + p]);
      fW1i.u[s]  = pk2(w1it[c0*16 + p], w1it[c1*16 + p]);
      fW1iN.u[s] = fW1i.u[s] ^ 0x80008000u;
      fW1xr.u[s] = pk2(W1xr[c0*16 + p], W1xr[c1*16 + p]);
      fW1xi.u[s] = pk2(W1xi[c0*16 + p], W1xi[c1*16 + p]);
    }
    #pragma unroll
    for (int mt = 0; mt < 2; ++mt) {
      int o = mt*16 + p;
      #pragma unroll
      for (int s = 0; s < 4; ++s) {
        int k0 = 8*q + 2*s;
        float a  = (k0   < 16) ? w2r[o*16 + k0]      : -w2i[o*16 + k0 - 16];
        float bb = (k0+1 < 16) ? w2r[o*16 + k0 + 1]  : -w2i[o*16 + k0 - 15];
        fW2[mt].u[s] = pk2(a, bb);
      }
    }
    float4 b1r4 = *(const float4*)(b1pr + 4*q);
    float4 b1i4 = *(const float4*)(b1pi + 4*q);
    float b2a[2][4], wga[2][4];
    #pragma unroll
    for (int mt = 0; mt < 2; ++mt) {
      float4 t0 = *(const float4*)(b2r + mt*16 + 4*q);
      float4 t1 = *(const float4*)(wgr + mt*16 + 4*q);
      b2a[mt][0]=t0.x; b2a[mt][1]=t0.y; b2a[mt][2]=t0.z; b2a[mt][3]=t0.w;
      wga[mt][0]=t1.x; wga[mt][1]=t1.y; wga[mt][2]=t1.z; wga[mt][3]=t1.w;
    }
    float b1ra[4] = {b1r4.x, b1r4.y, b1r4.z, b1r4.w};
    float b1ia[4] = {b1i4.x, b1i4.y, b1i4.z, b1i4.w};

    f32x4 zacc = {0.f, 0.f, 0.f, 0.f};
    const unsigned int* xlW = (const unsigned int*)xlT;

    for (int tt = 0; tt < 2; ++tt) {
      int tile = wv*2 + tt;
      int ya = tile >> 2, zg = tile & 3;
      int row = ya*64 + zg*16 + p;

      unsigned int w8[8];
      #pragma unroll
      for (int jj = 0; jj < 8; ++jj) w8[jj] = xfT[row*33 + 8*q + jj];
      U8 FR, FI, XV;
      #pragma unroll
      for (int s = 0; s < 4; ++s) {
        FR.u[s] = __builtin_amdgcn_perm(w8[2*s+1], w8[2*s], 0x05040100u);
        FI.u[s] = __builtin_amdgcn_perm(w8[2*s+1], w8[2*s], 0x07060302u);
        XV.u[s] = xlW[row*17 + 4*q + s];
      }

      f32x4 accR = zacc, accI = zacc;
      accR = __builtin_amdgcn_mfma_f32_16x16x32_bf16(fW1r.v,  FR.v, accR, 0, 0, 0);
      accR = __builtin_amdgcn_mfma_f32_16x16x32_bf16(fW1iN.v, FI.v, accR, 0, 0, 0);
      accR = __builtin_amdgcn_mfma_f32_16x16x32_bf16(fW1xr.v, XV.v, accR, 0, 0, 0);
      accI = __builtin_amdgcn_mfma_f32_16x16x32_bf16(fW1r.v,  FI.v, accI, 0, 0, 0);
      accI = __builtin_amdgcn_mfma_f32_16x16x32_bf16(fW1i.v,  FR.v, accI, 0, 0, 0);
      accI = __builtin_amdgcn_mfma_f32_16x16x32_bf16(fW1xi.v, XV.v, accI, 0, 0, 0);

      float hr_[4], hi_[4];
      #pragma unroll
      for (int r = 0; r < 4; ++r) {
        hr_[r] = geluf(accR[r] + b1ra[r]);
        hi_[r] = geluf(accI[r] + b1ia[r]);
      }
      // write H (C-layout -> [p][k] bf16), then read layer-2 B-fragment
      hpW[wb + 17*p + 2*q]     = pk2(hr_[0], hr_[1]);
      hpW[wb + 17*p + 2*q + 1] = pk2(hr_[2], hr_[3]);
      hpW[wb + 17*p + 8 + 2*q]     = pk2(hi_[0], hi_[1]);
      hpW[wb + 17*p + 8 + 2*q + 1] = pk2(hi_[2], hi_[3]);

      U8 FH;
      #pragma unroll
      for (int s = 0; s < 4; ++s) FH.u[s] = hpW[wb + 17*p + 4*q + s];

      #pragma unroll
      for (int mt = 0; mt < 2; ++mt) {
        f32x4 accO = __builtin_amdgcn_mfma_f32_16x16x32_bf16(fW2[mt].v, FH.v, zacc, 0, 0, 0);
        #pragma unroll
        for (int r = 0; r < 4; ++r) {
          int o = mt*16 + q*4 + r;
          int z = zg*16 + p;
          float xv = __bfloat162float(xlT[row*34 + o]);
          out[(size_t)(b*32 + o)*262144 + (size_t)xr*4096 + (size_t)(y0 + ya)*64 + z]
              = accO[r] + b2a[mt][r] + wga[mt][r]*xv;
        }
      }
    }
  }
}

// ---------------- launch ----------------
extern "C" void kernel_launch(void* const* d_in, const int* in_sizes, int n_in,
                              void* d_out, int out_size, void* d_ws, size_t ws_size,
                              hipStream_t stream) {
  (void)in_sizes; (void)n_in; (void)out_size; (void)ws_size;
  const float* x   = (const float*)d_in[0];
  const float* wfr = (const float*)d_in[1];
  const float* wfi = (const float*)d_in[2];
  const float* bfr = (const float*)d_in[3];
  const float* bfi = (const float*)d_in[4];
  const float* wgr = (const float*)d_in[5];
  const float* wsr = (const float*)d_in[7];
  const float* wsi = (const float*)d_in[8];
  const float* w1r = (const float*)d_in[9];
  const float* w1i = (const float*)d_in[10];
  const float* b1r = (const float*)d_in[11];
  const float* b1i = (const float*)d_in[12];
  const float* w2r = (const float*)d_in[13];
  const float* w2i = (const float*)d_in[14];
  const float* b2r = (const float*)d_in[15];
  float* out = (float*)d_out;
  float* ws  = (float*)d_ws;

  float* T1      = ws + O_T1;    // U2 home
  float* T2      = ws + O_T2;    // also U1
  float* xs      = ws + O_XS;
  float* xs2     = ws + O_XS2;
  float* coeffs  = ws + O_COEF;
  float* coeffs2 = ws + O_COEF2;
  float* Y       = ws + O_Y;
  int* shellOf   = (int*)(ws + O_SHELL);
  int* order     = (int*)(ws + O_ORDER);
  int* sstart    = (int*)(ws + O_SSTART);
  float* wsh     = ws + O_WSH;

  hipLaunchKernelGGL(k0_init,  dim3(1),    dim3(256), 0, stream, wfr, wfi, bfr, bfi, w1r, w1i, b1r, b1i, ws);
  hipLaunchKernelGGL(k12_fwd,  dim3(4096), dim3(256), 0, stream, x, T2);
  hipLaunchKernelGGL(k3_dftx,  dim3(1024), dim3(256), 0, stream, T2, xs);
  hipLaunchKernelGGL(k4_proj,  dim3(1024), dim3(256), 0, stream, xs, Y, order, sstart, wsh, coeffs);
  hipLaunchKernelGGL(k5_spec,  dim3(288),  dim3(64),  0, stream, coeffs, wsr, wsi, coeffs2);
  hipLaunchKernelGGL(k7_unproj,dim3(1024), dim3(256), 0, stream, coeffs2, Y, shellOf, wsh, xs2);
  hipLaunchKernelGGL(k8_invx,  dim3(1024), dim3(256), 0, stream, xs2, T2);
  hipLaunchKernelGGL(k9_invy,  dim3(4096), dim3(256), 0, stream, T2, T1);
  hipLaunchKernelGGL(k10_final,dim3(4096), dim3(256), 0, stream, x, T1, ws, w2r, w2i, b2r, wgr, out);
}